// Round 9
// baseline (223.472 us; speedup 1.0000x reference)
//
#include <hip/hip_runtime.h>
#include <hip/hip_bf16.h>
#include <stdint.h>

typedef __attribute__((ext_vector_type(8))) short bf16x8;   // 8 bf16 = 4 VGPRs
typedef __attribute__((ext_vector_type(4))) float f32x4;
typedef __attribute__((ext_vector_type(4))) unsigned u32x4;

#define MFMA16(A,B,C) __builtin_amdgcn_mfma_f32_16x16x32_bf16(A,B,C,0,0,0)

// Fragment layouts (verified m89/m91 ladder):
//  A-frag: lane l holds A[m=l&15][k=(l>>4)*8+j], j=0..7   (k-contiguous)
//  B-frag: lane l holds B^T[n=l&15][k=(l>>4)*8+j]         (k-contiguous)
//  C/D:    lane l reg r holds D[m=(l>>4)*4+r][n=l&15]

// async 16B global->LDS
__device__ inline void gld_lds16(const __hip_bfloat16* g, __hip_bfloat16* l) {
  __builtin_amdgcn_global_load_lds(
      (const __attribute__((address_space(1))) void*)g,
      (__attribute__((address_space(3))) void*)l, 16, 0, 0);
}

// 8 x f32 -> 8 x bf16, store 16B to LDS (fused cvt staging)
__device__ inline void cvt_store8(const float* __restrict__ g,
                                  __hip_bfloat16* __restrict__ l) {
  float4 u0 = *(const float4*)g;
  float4 u1 = *(const float4*)(g + 4);
  __hip_bfloat162 t[4];
  t[0] = __float22bfloat162_rn(float2{u0.x, u0.y});
  t[1] = __float22bfloat162_rn(float2{u0.z, u0.w});
  t[2] = __float22bfloat162_rn(float2{u1.x, u1.y});
  t[3] = __float22bfloat162_rn(float2{u1.z, u1.w});
  *(int4*)l = *(const int4*)t;
}

// fused split-kv combine staging: l <- (a + b) * rinv  (8 elems)
__device__ inline void comb_store8(const __hip_bfloat16* __restrict__ a,
                                   const __hip_bfloat16* __restrict__ b,
                                   float rinv,
                                   __hip_bfloat16* __restrict__ l) {
  int4 av = *(const int4*)a;
  int4 bv = *(const int4*)b;
  const __hip_bfloat162* ap = (const __hip_bfloat162*)&av;
  const __hip_bfloat162* bp = (const __hip_bfloat162*)&bv;
  __hip_bfloat162 t[4];
#pragma unroll
  for (int i = 0; i < 4; i++) {
    float2 fa = __bfloat1622float2(ap[i]);
    float2 fb = __bfloat1622float2(bp[i]);
    t[i] = __float22bfloat162_rn(float2{(fa.x + fb.x) * rinv,
                                        (fa.y + fb.y) * rinv});
  }
  *(int4*)l = *(const int4*)t;
}

// pack two f32 -> one b32 holding (bf16(a) | bf16(b)<<16)
__device__ inline unsigned pkbf(float a, float b) {
  __hip_bfloat162 t = __float22bfloat162_rn(float2{a, b});
  return *(unsigned*)&t;
}

// Quad redistribution for the S^T->A-frag transform (r8, verified).
__device__ inline void quad_mix(unsigned &a, unsigned &b) {
#if __has_builtin(__builtin_amdgcn_permlane32_swap) && __has_builtin(__builtin_amdgcn_permlane16_swap)
  auto r1 = __builtin_amdgcn_permlane32_swap(a, b, false, false);
  auto r2 = __builtin_amdgcn_permlane16_swap(r1[0], r1[1], false, false);
  a = r2[0];
  b = r2[1];
#else
  int lane = (int)(threadIdx.x & 63);
  int g = lane >> 4;
  int lm = lane & 15;
  int slo = (((g << 1) & 3) << 4) | lm;
  int shi = ((((g << 1) | 1) & 3) << 4) | lm;
  unsigned t0 = (unsigned)__shfl((int)a, slo, 64);
  unsigned t1 = (unsigned)__shfl((int)b, slo, 64);
  unsigned t2 = (unsigned)__shfl((int)a, shi, 64);
  unsigned t3 = (unsigned)__shfl((int)b, shi, 64);
  bool hi = g >= 2;
  unsigned na = hi ? t1 : t0;
  unsigned nb = hi ? t3 : t2;
  a = na;
  b = nb;
#endif
}

// ---------------------------------------------------------------------------
// GEMM 1 (QKV projection, fused f32->bf16 cvt in staging):
//   A = x (f32 [4096][1024]), B = W_attn (f32 [3072][1024])
//   C (bf16) = qkv; Q third pre-scaled by (1/8)*log2(e); V third (bn>=2048)
//   stored transposed into vtg[((b*16+h)*64+dd)*2048 + t].
// 128x128 tile, BK=32, reg-staging (buffer_load + cvt + ds_write_b128).
// ---------------------------------------------------------------------------
__global__ __launch_bounds__(256)
void gemm_qkv(const float* __restrict__ A,
              const float* __restrict__ B,
              __hip_bfloat16* __restrict__ C,
              __hip_bfloat16* __restrict__ vtg,
              int M, int N, int K)
{
  __shared__ __align__(16) __hip_bfloat16 As[128 * 32];
  __shared__ __align__(16) __hip_bfloat16 Bs[128 * 32];

  const int tid  = threadIdx.x;
  const int lane = tid & 63;
  const int w    = tid >> 6;
  const int lm   = lane & 15;
  const int g    = lane >> 4;

  const int bm = blockIdx.y * 128;
  const int bn = blockIdx.x * 128;
  const int rm = (w >> 1) * 64;
  const int cn = (w & 1) * 64;

  const int row0 = tid >> 2;           // 0..63
  const int kc   = (tid & 3) * 8;

  const f32x4 fzero = {0.0f, 0.0f, 0.0f, 0.0f};
  f32x4 acc[4][4];
  for (int i = 0; i < 4; i++)
    for (int j = 0; j < 4; j++)
      acc[i][j] = fzero;

  for (int k0 = 0; k0 < K; k0 += 32) {
    __syncthreads();
#pragma unroll
    for (int p = 0; p < 2; p++) {
      int row = row0 + 64 * p;
      cvt_store8(A + (size_t)(bm + row) * K + k0 + kc, &As[row * 32 + kc]);
      cvt_store8(B + (size_t)(bn + row) * K + k0 + kc, &Bs[row * 32 + kc]);
    }
    __syncthreads();

    bf16x8 af[4], bfr[4];
#pragma unroll
    for (int i = 0; i < 4; i++)
      af[i] = *(const bf16x8*)&As[(rm + 16 * i + lm) * 32 + 8 * g];
#pragma unroll
    for (int j = 0; j < 4; j++)
      bfr[j] = *(const bf16x8*)&Bs[(cn + 16 * j + lm) * 32 + 8 * g];
#pragma unroll
    for (int i = 0; i < 4; i++)
#pragma unroll
      for (int j = 0; j < 4; j++)
        acc[i][j] = MFMA16(af[i], bfr[j], acc[i][j]);
  }

  if (bn >= 2048) {   // V third -> transposed store
#pragma unroll
    for (int j = 0; j < 4; j++) {
      int colv = bn + cn + 16 * j + lm - 2048;   // h*64 + dd
      int vh = colv >> 6, dd = colv & 63;
#pragma unroll
      for (int i = 0; i < 4; i++) {
        int m0 = bm + rm + 16 * i + 4 * g;
        int bb = m0 >> 11, t0 = m0 & 2047;
        __hip_bfloat16 t4[4];
#pragma unroll
        for (int r = 0; r < 4; r++) t4[r] = __float2bfloat16(acc[i][j][r]);
        *(int2*)&vtg[((size_t)(bb * 16 + vh) * 64 + dd) * 2048 + t0] =
            *(const int2*)t4;
      }
    }
    return;
  }

  // Q pre-scale: 1/sqrt(64) * log2(e)  (softmax becomes exp2)
  const float qs = (bn < 1024) ? (0.125f * 1.4426950408889634f) : 1.0f;
#pragma unroll
  for (int j = 0; j < 4; j++) {
    int coln = bn + cn + 16 * j + lm;
#pragma unroll
    for (int i = 0; i < 4; i++) {
#pragma unroll
      for (int r = 0; r < 4; r++) {
        int rowm = bm + rm + 16 * i + 4 * g + r;
        C[(size_t)rowm * N + coln] = __float2bfloat16(acc[i][j][r] * qs);
      }
    }
  }
}

// ---------------------------------------------------------------------------
// GEMM 2 (output projection, fused split-kv combine + f32 weight cvt):
//   A[m][k] = (Oa[m][k] + Ob[m][k]) * rinv(m, k>>6)   (built in staging)
//   B = W_proj (f32 [1024][1024]); out (f32) += bias.
// 128x128 tile, BK=32.
// ---------------------------------------------------------------------------
__global__ __launch_bounds__(256)
void gemm_out(const __hip_bfloat16* __restrict__ po,   // 2 x [4096][1024]
              const float* __restrict__ pl,            // 2 x [4096][16]
              const float* __restrict__ Bw,
              const float* __restrict__ bias,
              float* __restrict__ out,
              int M, int N, int K)
{
  __shared__ __align__(16) __hip_bfloat16 As[128 * 32];
  __shared__ __align__(16) __hip_bfloat16 Bs[128 * 32];

  const int tid  = threadIdx.x;
  const int lane = tid & 63;
  const int w    = tid >> 6;
  const int lm   = lane & 15;
  const int g    = lane >> 4;

  const int bm = blockIdx.y * 128;
  const int bn = blockIdx.x * 128;
  const int rm = (w >> 1) * 64;
  const int cn = (w & 1) * 64;

  const int row0 = tid >> 2;
  const int kc   = (tid & 3) * 8;

  const f32x4 fzero = {0.0f, 0.0f, 0.0f, 0.0f};
  f32x4 acc[4][4];
  for (int i = 0; i < 4; i++)
    for (int j = 0; j < 4; j++)
      acc[i][j] = fzero;

  for (int k0 = 0; k0 < K; k0 += 32) {
    const int h = (k0 + kc) >> 6;
    __syncthreads();
#pragma unroll
    for (int p = 0; p < 2; p++) {
      int row = row0 + 64 * p;
      int m = bm + row;
      float la = pl[m * 16 + h];
      float lb = pl[4096 * 16 + m * 16 + h];
      float rinv = 1.0f / (la + lb);
      comb_store8(po + (size_t)m * 1024 + k0 + kc,
                  po + (size_t)4096 * 1024 + (size_t)m * 1024 + k0 + kc,
                  rinv, &As[row * 32 + kc]);
      cvt_store8(Bw + (size_t)(bn + row) * K + k0 + kc, &Bs[row * 32 + kc]);
    }
    __syncthreads();

    bf16x8 af[4], bfr[4];
#pragma unroll
    for (int i = 0; i < 4; i++)
      af[i] = *(const bf16x8*)&As[(rm + 16 * i + lm) * 32 + 8 * g];
#pragma unroll
    for (int j = 0; j < 4; j++)
      bfr[j] = *(const bf16x8*)&Bs[(cn + 16 * j + lm) * 32 + 8 * g];
#pragma unroll
    for (int i = 0; i < 4; i++)
#pragma unroll
      for (int j = 0; j < 4; j++)
        acc[i][j] = MFMA16(af[i], bfr[j], acc[i][j]);
  }

#pragma unroll
  for (int j = 0; j < 4; j++) {
    int coln = bn + cn + 16 * j + lm;
    float bv = bias[coln];
#pragma unroll
    for (int i = 0; i < 4; i++) {
#pragma unroll
      for (int r = 0; r < 4; r++) {
        int rowm = bm + rm + 16 * i + 4 * g + r;
        out[(size_t)rowm * N + coln] = acc[i][j][r] + bv;
      }
    }
  }
}

// ---------------------------------------------------------------------------
// MHA (r8 structure, partial-output only), no-max softmax, S^T formulation:
//   S^T = K·Q^T ; p = exp2(s) (log2e folded into Q); C->A via quad_mix; O = P·V
// Block = (b,h) x 128 q x kv-slice(z); wave owns 32 q; kv-step 32.
// Writes unnormalized partial O (bf16) to po[z] and row-sums l to pl[z].
// ---------------------------------------------------------------------------
__global__ __launch_bounds__(256)
void mha(const __hip_bfloat16* __restrict__ qkv,
         const __hip_bfloat16* __restrict__ vtg,
         __hip_bfloat16* __restrict__ po,
         float* __restrict__ pl,
         int nsteps)
{
  const int T = 2048, F = 3072, Cc = 1024;
  const int bh = blockIdx.x;
  const int b  = bh >> 4, h = bh & 15;
  const int qb0 = blockIdx.y * 128;
  const int z   = blockIdx.z;
  const int kvb = z * 32 * nsteps;

  const int tid  = threadIdx.x;
  const int lane = tid & 63;
  const int w    = tid >> 6;
  const int lm   = lane & 15;
  const int g    = lane >> 4;

  __shared__ __align__(16) __hip_bfloat16 Ks[2][32 * 64];   // 8 KB
  __shared__ __align__(16) __hip_bfloat16 Vs[2][64 * 32];   // 8 KB

  const size_t rowbase = (size_t)b * T * F;
  const int hoff = h * 64;
  const __hip_bfloat16* Kbase = qkv + rowbase + 1024 + hoff;
  const __hip_bfloat16* Vtb   = vtg + (size_t)(b * 16 + h) * 64 * 2048;

  const int qw = qb0 + 32 * w;
  bf16x8 aq[2][2];
#pragma unroll
  for (int mt = 0; mt < 2; mt++)
#pragma unroll
    for (int e = 0; e < 2; e++)
      aq[mt][e] = *(const bf16x8*)
          &qkv[rowbase + (size_t)(qw + 16 * mt + lm) * F + hoff + 32 * e + 8 * g];

  const f32x4 fzero = {0.0f, 0.0f, 0.0f, 0.0f};
  f32x4 yacc[2][4];
  float lsum[2] = {0.0f, 0.0f};
#pragma unroll
  for (int mt = 0; mt < 2; mt++)
#pragma unroll
    for (int c = 0; c < 4; c++) yacc[mt][c] = fzero;

  const int r0  = tid >> 3;
  const int swK = (tid & 7) ^ (r0 & 7);
  const int vdd = tid >> 2;
  const int vk  = (tid & 3) ^ ((tid >> 3) & 3);
  const int sxK = lm & 7;
  const int sxV = (lm >> 1) & 3;

  gld_lds16(Kbase + (size_t)(kvb + r0) * F + swK * 8, &Ks[0][tid * 8]);
  gld_lds16(Vtb + (size_t)vdd * 2048 + kvb + vk * 8, &Vs[0][tid * 8]);

  for (int t = 0; t < nsteps; t++) {
    const int buf = t & 1;
    __syncthreads();
    if (t + 1 < nsteps) {
      const int kvn = kvb + (t + 1) * 32;
      gld_lds16(Kbase + (size_t)(kvn + r0) * F + swK * 8, &Ks[buf ^ 1][tid * 8]);
      gld_lds16(Vtb + (size_t)vdd * 2048 + kvn + vk * 8, &Vs[buf ^ 1][tid * 8]);
    }

    bf16x8 kf[2][2];
#pragma unroll
    for (int c2 = 0; c2 < 2; c2++) {
      kf[c2][0] = *(const bf16x8*)&Ks[buf][(16 * c2 + lm) * 64 + ((0 + g) ^ sxK) * 8];
      kf[c2][1] = *(const bf16x8*)&Ks[buf][(16 * c2 + lm) * 64 + ((4 + g) ^ sxK) * 8];
    }
#pragma unroll
    for (int mt = 0; mt < 2; mt++) {
      f32x4 st[2];
#pragma unroll
      for (int c2 = 0; c2 < 2; c2++) {
        st[c2] = MFMA16(kf[c2][0], aq[mt][0], fzero);
        st[c2] = MFMA16(kf[c2][1], aq[mt][1], st[c2]);
      }

      unsigned pkv[2][2];
#pragma unroll
      for (int c2 = 0; c2 < 2; c2++)
#pragma unroll
        for (int u = 0; u < 2; u++) {
          float p0 = __builtin_amdgcn_exp2f(st[c2][2 * u]);
          float p1 = __builtin_amdgcn_exp2f(st[c2][2 * u + 1]);
          lsum[mt] += p0 + p1;
          pkv[c2][u] = pkbf(p0, p1);
        }

      unsigned f0 = pkv[0][0], f2 = pkv[1][0];
      quad_mix(f0, f2);
      unsigned f1 = pkv[0][1], f3 = pkv[1][1];
      quad_mix(f1, f3);
      u32x4 fv = {f0, f1, f2, f3};
      bf16x8 ap = __builtin_bit_cast(bf16x8, fv);

#pragma unroll
      for (int c = 0; c < 4; c++) {
        bf16x8 bv = *(const bf16x8*)&Vs[buf][(16 * c + lm) * 32 + (g ^ sxV) * 8];
        yacc[mt][c] = MFMA16(ap, bv, yacc[mt][c]);
      }
    }
  }

  float lred[2];
#pragma unroll
  for (int mt = 0; mt < 2; mt++) {
    float ls = lsum[mt];
    ls += __shfl_xor(ls, 16);
    ls += __shfl_xor(ls, 32);
    lred[mt] = ls;
  }

  __hip_bfloat16* pz = po + (size_t)z * 4096 * 1024;
  float* plz = pl + (size_t)z * 4096 * 16;
#pragma unroll
  for (int mt = 0; mt < 2; mt++) {
#pragma unroll
    for (int c = 0; c < 4; c++)
#pragma unroll
      for (int r = 0; r < 4; r++) {
        int qrow = qw + 16 * mt + 4 * g + r;
        pz[(size_t)(b * T + qrow) * Cc + hoff + 16 * c + lm] =
            __float2bfloat16(yacc[mt][c][r]);
      }
    if (lane < 16)
      plz[(b * T + qw + 16 * mt + lane) * 16 + h] = lred[mt];
  }
}

// ---------------------------------------------------------------------------
extern "C" void kernel_launch(void* const* d_in, const int* in_sizes, int n_in,
                              void* d_out, int out_size, void* d_ws, size_t ws_size,
                              hipStream_t stream)
{
  const float* x  = (const float*)d_in[0];   // [2,2048,1024]
  const float* Wa = (const float*)d_in[1];   // [3072,1024]
  const float* Wp = (const float*)d_in[2];   // [1024,1024]
  const float* bp = (const float*)d_in[3];   // [1024]
  float* out = (float*)d_out;                // [2,2048,1024] f32

  const int BT = 4096, C = 1024, F3 = 3072;
  char* ws = (char*)d_ws;
  __hip_bfloat16* qkv  = (__hip_bfloat16*)ws;                // 25.2 MB (V third unwritten)
  __hip_bfloat16* vtg  = (__hip_bfloat16*)(ws + 25165824);   // 8.4 MB V^T
  __hip_bfloat16* Opar = (__hip_bfloat16*)(ws + 33554432);   // 2 x 8.4 MB
  float*          lpar = (float*)(ws + 50331648);            // 2 x 256 KB
  // total 50.8 MB (< provided ws; rounds 6-8 confirmed >= 67.6 MB available)

  // 1) QKV projection (fused f32->bf16; Q pre-scaled; V stored transposed)
  gemm_qkv<<<dim3(F3 / 128, BT / 128), 256, 0, stream>>>(x, Wa, qkv, vtg,
                                                         BT, F3, C);
  // 2) attention, split-kv 2-way -> partials
  mha<<<dim3(32, 16, 2), 256, 0, stream>>>(qkv, vtg, Opar, lpar, 32);
  // 3) output projection (fused combine + f32 weight cvt + bias)
  gemm_out<<<dim3(C / 128, BT / 128), 256, 0, stream>>>(Opar, lpar, Wp, bp, out,
                                                        BT, C, C);
}

// Round 10
// 209.202 us; speedup vs baseline: 1.0682x; 1.0682x over previous
//
#include <hip/hip_runtime.h>
#include <hip/hip_bf16.h>
#include <stdint.h>

typedef __attribute__((ext_vector_type(8))) short bf16x8;   // 8 bf16 = 4 VGPRs
typedef __attribute__((ext_vector_type(4))) float f32x4;
typedef __attribute__((ext_vector_type(4))) unsigned u32x4;

#define MFMA16(A,B,C) __builtin_amdgcn_mfma_f32_16x16x32_bf16(A,B,C,0,0,0)

// Fragment layouts (verified m89/m91 ladder):
//  A-frag: lane l holds A[m=l&15][k=(l>>4)*8+j], j=0..7   (k-contiguous)
//  B-frag: lane l holds B^T[n=l&15][k=(l>>4)*8+j]         (k-contiguous)
//  C/D:    lane l reg r holds D[m=(l>>4)*4+r][n=l&15]

// async 16B global->LDS (mha staging)
__device__ inline void gld_lds16(const __hip_bfloat16* g, __hip_bfloat16* l) {
  __builtin_amdgcn_global_load_lds(
      (const __attribute__((address_space(1))) void*)g,
      (__attribute__((address_space(3))) void*)l, 16, 0, 0);
}

// 8 f32 (in regs) -> 8 bf16, 16B LDS store
__device__ inline void cvt_store8r(float4 u0, float4 u1,
                                   __hip_bfloat16* __restrict__ l) {
  __hip_bfloat162 t[4];
  t[0] = __float22bfloat162_rn(float2{u0.x, u0.y});
  t[1] = __float22bfloat162_rn(float2{u0.z, u0.w});
  t[2] = __float22bfloat162_rn(float2{u1.x, u1.y});
  t[3] = __float22bfloat162_rn(float2{u1.z, u1.w});
  *(int4*)l = *(const int4*)t;
}

// fused split-kv combine (regs): l <- (a + b) * rinv  (8 bf16 elems)
__device__ inline void comb_store8r(int4 av, int4 bv, float rinv,
                                    __hip_bfloat16* __restrict__ l) {
  const __hip_bfloat162* ap = (const __hip_bfloat162*)&av;
  const __hip_bfloat162* bp = (const __hip_bfloat162*)&bv;
  __hip_bfloat162 t[4];
#pragma unroll
  for (int i = 0; i < 4; i++) {
    float2 fa = __bfloat1622float2(ap[i]);
    float2 fb = __bfloat1622float2(bp[i]);
    t[i] = __float22bfloat162_rn(float2{(fa.x + fb.x) * rinv,
                                        (fa.y + fb.y) * rinv});
  }
  *(int4*)l = *(const int4*)t;
}

// pack two f32 -> one b32 holding (bf16(a) | bf16(b)<<16)
__device__ inline unsigned pkbf(float a, float b) {
  __hip_bfloat162 t = __float22bfloat162_rn(float2{a, b});
  return *(unsigned*)&t;
}

// Quad redistribution for the S^T->A-frag transform (r8, verified).
__device__ inline void quad_mix(unsigned &a, unsigned &b) {
#if __has_builtin(__builtin_amdgcn_permlane32_swap) && __has_builtin(__builtin_amdgcn_permlane16_swap)
  auto r1 = __builtin_amdgcn_permlane32_swap(a, b, false, false);
  auto r2 = __builtin_amdgcn_permlane16_swap(r1[0], r1[1], false, false);
  a = r2[0];
  b = r2[1];
#else
  int lane = (int)(threadIdx.x & 63);
  int g = lane >> 4;
  int lm = lane & 15;
  int slo = (((g << 1) & 3) << 4) | lm;
  int shi = ((((g << 1) | 1) & 3) << 4) | lm;
  unsigned t0 = (unsigned)__shfl((int)a, slo, 64);
  unsigned t1 = (unsigned)__shfl((int)b, slo, 64);
  unsigned t2 = (unsigned)__shfl((int)a, shi, 64);
  unsigned t3 = (unsigned)__shfl((int)b, shi, 64);
  bool hi = g >= 2;
  unsigned na = hi ? t1 : t0;
  unsigned nb = hi ? t3 : t2;
  a = na;
  b = nb;
#endif
}

// ---------------------------------------------------------------------------
// GEMM 1 (QKV projection, fused f32->bf16 cvt, reg-prefetch pipelined):
//   prefetch tile t+1 into regs during tile t's MFMA phase -> load latency
//   hidden behind compute (fixes r9's exposed vmcnt stall).
// 128x128 tile, BK=32. Q pre-scaled by (1/8)*log2e; V third -> vtg transposed.
// ---------------------------------------------------------------------------
__global__ __launch_bounds__(256)
void gemm_qkv(const float* __restrict__ A,
              const float* __restrict__ B,
              __hip_bfloat16* __restrict__ C,
              __hip_bfloat16* __restrict__ vtg,
              int M, int N, int K)
{
  __shared__ __align__(16) __hip_bfloat16 As[128 * 32];
  __shared__ __align__(16) __hip_bfloat16 Bs[128 * 32];

  const int tid  = threadIdx.x;
  const int lane = tid & 63;
  const int w    = tid >> 6;
  const int lm   = lane & 15;
  const int g    = lane >> 4;

  const int bm = blockIdx.y * 128;
  const int bn = blockIdx.x * 128;
  const int rm = (w >> 1) * 64;
  const int cn = (w & 1) * 64;

  const int row0 = tid >> 2;           // 0..63 (rows row0, row0+64)
  const int kc   = (tid & 3) * 8;

  float4 pa[2][2], pb[2][2];
  auto ldtile = [&](int k0) {
#pragma unroll
    for (int p = 0; p < 2; p++) {
      const float* ga = A + (size_t)(bm + row0 + 64 * p) * K + k0 + kc;
      pa[p][0] = *(const float4*)ga;
      pa[p][1] = *(const float4*)(ga + 4);
      const float* gb = B + (size_t)(bn + row0 + 64 * p) * K + k0 + kc;
      pb[p][0] = *(const float4*)gb;
      pb[p][1] = *(const float4*)(gb + 4);
    }
  };

  const f32x4 fzero = {0.0f, 0.0f, 0.0f, 0.0f};
  f32x4 acc[4][4];
  for (int i = 0; i < 4; i++)
    for (int j = 0; j < 4; j++)
      acc[i][j] = fzero;

  ldtile(0);
  for (int k0 = 0; k0 < K; k0 += 32) {
#pragma unroll
    for (int p = 0; p < 2; p++) {
      int row = row0 + 64 * p;
      cvt_store8r(pa[p][0], pa[p][1], &As[row * 32 + kc]);
      cvt_store8r(pb[p][0], pb[p][1], &Bs[row * 32 + kc]);
    }
    __syncthreads();                 // LDS tile ready
    if (k0 + 32 < K) ldtile(k0 + 32);   // prefetch: in flight through MFMA phase

    bf16x8 af[4], bfr[4];
#pragma unroll
    for (int i = 0; i < 4; i++)
      af[i] = *(const bf16x8*)&As[(rm + 16 * i + lm) * 32 + 8 * g];
#pragma unroll
    for (int j = 0; j < 4; j++)
      bfr[j] = *(const bf16x8*)&Bs[(cn + 16 * j + lm) * 32 + 8 * g];
#pragma unroll
    for (int i = 0; i < 4; i++)
#pragma unroll
      for (int j = 0; j < 4; j++)
        acc[i][j] = MFMA16(af[i], bfr[j], acc[i][j]);
    __syncthreads();                 // all reads done before next overwrite
  }

  if (bn >= 2048) {   // V third -> transposed store
#pragma unroll
    for (int j = 0; j < 4; j++) {
      int colv = bn + cn + 16 * j + lm - 2048;   // h*64 + dd
      int vh = colv >> 6, dd = colv & 63;
#pragma unroll
      for (int i = 0; i < 4; i++) {
        int m0 = bm + rm + 16 * i + 4 * g;
        int bb = m0 >> 11, t0 = m0 & 2047;
        __hip_bfloat16 t4[4];
#pragma unroll
        for (int r = 0; r < 4; r++) t4[r] = __float2bfloat16(acc[i][j][r]);
        *(int2*)&vtg[((size_t)(bb * 16 + vh) * 64 + dd) * 2048 + t0] =
            *(const int2*)t4;
      }
    }
    return;
  }

  const float qs = (bn < 1024) ? (0.125f * 1.4426950408889634f) : 1.0f;
#pragma unroll
  for (int j = 0; j < 4; j++) {
    int coln = bn + cn + 16 * j + lm;
#pragma unroll
    for (int i = 0; i < 4; i++) {
#pragma unroll
      for (int r = 0; r < 4; r++) {
        int rowm = bm + rm + 16 * i + 4 * g + r;
        C[(size_t)rowm * N + coln] = __float2bfloat16(acc[i][j][r] * qs);
      }
    }
  }
}

// ---------------------------------------------------------------------------
// GEMM 2 (output projection, fused combine, reg-prefetch pipelined):
//   A[m][k] = (Oa+Ob)*rinv built in staging; B = W_proj f32 cvt in staging.
// 128x64 tile -> grid (16,32)=512 blocks (2/CU; fixes r9's 1-block/CU stall).
// Wave tile 64x32: 8 MFMA/step. LDS 12 KB.
// ---------------------------------------------------------------------------
__global__ __launch_bounds__(256)
void gemm_out(const __hip_bfloat16* __restrict__ po,   // 2 x [4096][1024]
              const float* __restrict__ pl,            // 2 x [4096][16]
              const float* __restrict__ Bw,
              const float* __restrict__ bias,
              float* __restrict__ out,
              int M, int N, int K)
{
  __shared__ __align__(16) __hip_bfloat16 As[128 * 32];   // 8 KB
  __shared__ __align__(16) __hip_bfloat16 Bs[64 * 32];    // 4 KB

  const int tid  = threadIdx.x;
  const int lane = tid & 63;
  const int w    = tid >> 6;
  const int lm   = lane & 15;
  const int g    = lane >> 4;

  const int bm = blockIdx.y * 128;
  const int bn = blockIdx.x * 64;
  const int rm = (w >> 1) * 64;    // wave m-offset
  const int cn = (w & 1) * 32;     // wave n-offset

  const int row0 = tid >> 2;       // 0..63
  const int kc   = (tid & 3) * 8;

  int4  qa[2], qb[2];              // po halves, rows row0, row0+64
  float la[2], lb[2];
  float4 wb0, wb1;                 // W_proj row row0 (8 f32)
  auto ldtile = [&](int k0) {
    const int h = k0 >> 6;
#pragma unroll
    for (int p = 0; p < 2; p++) {
      int m = bm + row0 + 64 * p;
      qa[p] = *(const int4*)(po + (size_t)m * 1024 + k0 + kc);
      qb[p] = *(const int4*)(po + (size_t)4096 * 1024 + (size_t)m * 1024 + k0 + kc);
      la[p] = pl[m * 16 + h];
      lb[p] = pl[4096 * 16 + m * 16 + h];
    }
    const float* gb = Bw + (size_t)(bn + row0) * K + k0 + kc;
    wb0 = *(const float4*)gb;
    wb1 = *(const float4*)(gb + 4);
  };

  const f32x4 fzero = {0.0f, 0.0f, 0.0f, 0.0f};
  f32x4 acc[4][2];
  for (int i = 0; i < 4; i++)
    for (int j = 0; j < 2; j++)
      acc[i][j] = fzero;

  ldtile(0);
  for (int k0 = 0; k0 < K; k0 += 32) {
#pragma unroll
    for (int p = 0; p < 2; p++)
      comb_store8r(qa[p], qb[p], 1.0f / (la[p] + lb[p]),
                   &As[(row0 + 64 * p) * 32 + kc]);
    cvt_store8r(wb0, wb1, &Bs[row0 * 32 + kc]);
    __syncthreads();
    if (k0 + 32 < K) ldtile(k0 + 32);

    bf16x8 af[4], bfr[2];
#pragma unroll
    for (int i = 0; i < 4; i++)
      af[i] = *(const bf16x8*)&As[(rm + 16 * i + lm) * 32 + 8 * g];
#pragma unroll
    for (int j = 0; j < 2; j++)
      bfr[j] = *(const bf16x8*)&Bs[(cn + 16 * j + lm) * 32 + 8 * g];
#pragma unroll
    for (int i = 0; i < 4; i++)
#pragma unroll
      for (int j = 0; j < 2; j++)
        acc[i][j] = MFMA16(af[i], bfr[j], acc[i][j]);
    __syncthreads();
  }

#pragma unroll
  for (int j = 0; j < 2; j++) {
    int coln = bn + cn + 16 * j + lm;
    float bv = bias[coln];
#pragma unroll
    for (int i = 0; i < 4; i++) {
#pragma unroll
      for (int r = 0; r < 4; r++) {
        int rowm = bm + rm + 16 * i + 4 * g + r;
        out[(size_t)rowm * N + coln] = acc[i][j][r] + bv;
      }
    }
  }
}

// ---------------------------------------------------------------------------
// MHA (r8 structure, unchanged): no-max softmax, S^T formulation, quad_mix
// C->A transform, kv-step 32, split-kv 2-way partials.
// ---------------------------------------------------------------------------
__global__ __launch_bounds__(256)
void mha(const __hip_bfloat16* __restrict__ qkv,
         const __hip_bfloat16* __restrict__ vtg,
         __hip_bfloat16* __restrict__ po,
         float* __restrict__ pl,
         int nsteps)
{
  const int T = 2048, F = 3072, Cc = 1024;
  const int bh = blockIdx.x;
  const int b  = bh >> 4, h = bh & 15;
  const int qb0 = blockIdx.y * 128;
  const int z   = blockIdx.z;
  const int kvb = z * 32 * nsteps;

  const int tid  = threadIdx.x;
  const int lane = tid & 63;
  const int w    = tid >> 6;
  const int lm   = lane & 15;
  const int g    = lane >> 4;

  __shared__ __align__(16) __hip_bfloat16 Ks[2][32 * 64];   // 8 KB
  __shared__ __align__(16) __hip_bfloat16 Vs[2][64 * 32];   // 8 KB

  const size_t rowbase = (size_t)b * T * F;
  const int hoff = h * 64;
  const __hip_bfloat16* Kbase = qkv + rowbase + 1024 + hoff;
  const __hip_bfloat16* Vtb   = vtg + (size_t)(b * 16 + h) * 64 * 2048;

  const int qw = qb0 + 32 * w;
  bf16x8 aq[2][2];
#pragma unroll
  for (int mt = 0; mt < 2; mt++)
#pragma unroll
    for (int e = 0; e < 2; e++)
      aq[mt][e] = *(const bf16x8*)
          &qkv[rowbase + (size_t)(qw + 16 * mt + lm) * F + hoff + 32 * e + 8 * g];

  const f32x4 fzero = {0.0f, 0.0f, 0.0f, 0.0f};
  f32x4 yacc[2][4];
  float lsum[2] = {0.0f, 0.0f};
#pragma unroll
  for (int mt = 0; mt < 2; mt++)
#pragma unroll
    for (int c = 0; c < 4; c++) yacc[mt][c] = fzero;

  const int r0  = tid >> 3;
  const int swK = (tid & 7) ^ (r0 & 7);
  const int vdd = tid >> 2;
  const int vk  = (tid & 3) ^ ((tid >> 3) & 3);
  const int sxK = lm & 7;
  const int sxV = (lm >> 1) & 3;

  gld_lds16(Kbase + (size_t)(kvb + r0) * F + swK * 8, &Ks[0][tid * 8]);
  gld_lds16(Vtb + (size_t)vdd * 2048 + kvb + vk * 8, &Vs[0][tid * 8]);

  for (int t = 0; t < nsteps; t++) {
    const int buf = t & 1;
    __syncthreads();
    if (t + 1 < nsteps) {
      const int kvn = kvb + (t + 1) * 32;
      gld_lds16(Kbase + (size_t)(kvn + r0) * F + swK * 8, &Ks[buf ^ 1][tid * 8]);
      gld_lds16(Vtb + (size_t)vdd * 2048 + kvn + vk * 8, &Vs[buf ^ 1][tid * 8]);
    }

    bf16x8 kf[2][2];
#pragma unroll
    for (int c2 = 0; c2 < 2; c2++) {
      kf[c2][0] = *(const bf16x8*)&Ks[buf][(16 * c2 + lm) * 64 + ((0 + g) ^ sxK) * 8];
      kf[c2][1] = *(const bf16x8*)&Ks[buf][(16 * c2 + lm) * 64 + ((4 + g) ^ sxK) * 8];
    }
#pragma unroll
    for (int mt = 0; mt < 2; mt++) {
      f32x4 st[2];
#pragma unroll
      for (int c2 = 0; c2 < 2; c2++) {
        st[c2] = MFMA16(kf[c2][0], aq[mt][0], fzero);
        st[c2] = MFMA16(kf[c2][1], aq[mt][1], st[c2]);
      }

      unsigned pkv[2][2];
#pragma unroll
      for (int c2 = 0; c2 < 2; c2++)
#pragma unroll
        for (int u = 0; u < 2; u++) {
          float p0 = __builtin_amdgcn_exp2f(st[c2][2 * u]);
          float p1 = __builtin_amdgcn_exp2f(st[c2][2 * u + 1]);
          lsum[mt] += p0 + p1;
          pkv[c2][u] = pkbf(p0, p1);
        }

      unsigned f0 = pkv[0][0], f2 = pkv[1][0];
      quad_mix(f0, f2);
      unsigned f1 = pkv[0][1], f3 = pkv[1][1];
      quad_mix(f1, f3);
      u32x4 fv = {f0, f1, f2, f3};
      bf16x8 ap = __builtin_bit_cast(bf16x8, fv);

#pragma unroll
      for (int c = 0; c < 4; c++) {
        bf16x8 bv = *(const bf16x8*)&Vs[buf][(16 * c + lm) * 32 + (g ^ sxV) * 8];
        yacc[mt][c] = MFMA16(ap, bv, yacc[mt][c]);
      }
    }
  }

  float lred[2];
#pragma unroll
  for (int mt = 0; mt < 2; mt++) {
    float ls = lsum[mt];
    ls += __shfl_xor(ls, 16);
    ls += __shfl_xor(ls, 32);
    lred[mt] = ls;
  }

  __hip_bfloat16* pz = po + (size_t)z * 4096 * 1024;
  float* plz = pl + (size_t)z * 4096 * 16;
#pragma unroll
  for (int mt = 0; mt < 2; mt++) {
#pragma unroll
    for (int c = 0; c < 4; c++)
#pragma unroll
      for (int r = 0; r < 4; r++) {
        int qrow = qw + 16 * mt + 4 * g + r;
        pz[(size_t)(b * T + qrow) * Cc + hoff + 16 * c + lm] =
            __float2bfloat16(yacc[mt][c][r]);
      }
    if (lane < 16)
      plz[(b * T + qw + 16 * mt + lane) * 16 + h] = lred[mt];
  }
}

// ---------------------------------------------------------------------------
extern "C" void kernel_launch(void* const* d_in, const int* in_sizes, int n_in,
                              void* d_out, int out_size, void* d_ws, size_t ws_size,
                              hipStream_t stream)
{
  const float* x  = (const float*)d_in[0];   // [2,2048,1024]
  const float* Wa = (const float*)d_in[1];   // [3072,1024]
  const float* Wp = (const float*)d_in[2];   // [1024,1024]
  const float* bp = (const float*)d_in[3];   // [1024]
  float* out = (float*)d_out;                // [2,2048,1024] f32

  const int BT = 4096, C = 1024, F3 = 3072;
  char* ws = (char*)d_ws;
  __hip_bfloat16* qkv  = (__hip_bfloat16*)ws;                // 25.2 MB (V third unwritten)
  __hip_bfloat16* vtg  = (__hip_bfloat16*)(ws + 25165824);   // 8.4 MB V^T
  __hip_bfloat16* Opar = (__hip_bfloat16*)(ws + 33554432);   // 2 x 8.4 MB
  float*          lpar = (float*)(ws + 50331648);            // 2 x 256 KB

  // 1) QKV projection (pipelined fused-cvt; Q pre-scaled; V transposed)
  gemm_qkv<<<dim3(F3 / 128, BT / 128), 256, 0, stream>>>(x, Wa, qkv, vtg,
                                                         BT, F3, C);
  // 2) attention, split-kv 2-way -> partials
  mha<<<dim3(32, 16, 2), 256, 0, stream>>>(qkv, vtg, Opar, lpar, 32);
  // 3) output projection (pipelined fused combine + cvt + bias), 128x64 tiles
  gemm_out<<<dim3(C / 64, BT / 128), 256, 0, stream>>>(Opar, lpar, Wp, bp, out,
                                                       BT, C, C);
}